// Round 13
// baseline (138.482 us; speedup 1.0000x reference)
//
#include <hip/hip_runtime.h>
#include <hip/hip_bf16.h>

// Problem: features_1 [1,20000,256] f32, features_2 [1,8192,256] f32, map21 [8192] int
#define PP      8192
#define DIM     256
#define DIMP    272              // 256 + 16 pad dims (norm embedding in 4 of them)
#define NKF     17               // K fragments of 16
#define GS      (32 * DIMP)      // 8704 bf16 elems per 32-row group
#define NSTRIPE 16               // col-stripes; stripe = 16 col-groups = 512 cols
#define TPC     16               // col-group tiles per stripe
#define ROWBLK  256              // rows per block (4 waves x 2 row-groups)
#define NROWBLK (PP / ROWBLK)    // 32

typedef __bf16 bf16_t;
using bf16x8 = __attribute__((ext_vector_type(8))) __bf16;
using bf16x4 = __attribute__((ext_vector_type(4))) __bf16;
using f32x4  = __attribute__((ext_vector_type(4))) float;
using f32x16 = __attribute__((ext_vector_type(16))) float;

#define C2    20.609929155556618          // 1/(T*ln2): -dist -> log2-domain logit
#define MEXP  (-340.0f)                   // fixed log2 shift (safe: see analysis)
#define COEF  ((float)(-(C2 * 1.4142135623730951) * 8388608.0))  // -C2*sqrt(2)*2^23
#define KBIAS ((float)((127.0 + 340.0) * 8388608.0))             // (127 - MEXP)*2^23
#define LN2   0.6931471805599453f

// ---------------------------------------------------------------------------
// Kernel 1: gather + bf16 convert into frag-major layout + norm-embedding pad
// dims + exact fp32 diagonal logit. Also zero-inits part_l / counters / out.
// One wave per row p; lane covers k = lane*4 .. +3.   (UNCHANGED)
// ---------------------------------------------------------------------------
__global__ __launch_bounds__(256) void nce_prep(
    const float* __restrict__ f1, const float* __restrict__ f2,
    const int* __restrict__ map,
    bf16_t* __restrict__ qb2, bf16_t* __restrict__ kb2,
    float* __restrict__ diag2, float* __restrict__ part_l,
    unsigned* __restrict__ cnt, float* __restrict__ out)
{
    const int tid  = threadIdx.x;
    const int wave = tid >> 6, lane = tid & 63;
    const int p    = blockIdx.x * 4 + wave;
    const int gtid = blockIdx.x * 256 + tid;

    if (gtid < PP) part_l[gtid] = 0.0f;
    if (gtid < NROWBLK) cnt[gtid] = 0u;
    if (gtid == 0) out[0] = 0.0f;

    const int idx = map[p];
    const f32x4 qv = *(const f32x4*)(f1 + (size_t)idx * DIM + lane * 4);
    const f32x4 kv = *(const f32x4*)(f2 + (size_t)p * DIM + lane * 4);

    float qs = qv[0]*qv[0] + qv[1]*qv[1] + qv[2]*qv[2] + qv[3]*qv[3];
    float ks = kv[0]*kv[0] + kv[1]*kv[1] + kv[2]*kv[2] + kv[3]*kv[3];
    const f32x4 dv = qv - kv;
    float ds = dv[0]*dv[0] + dv[1]*dv[1] + dv[2]*dv[2] + dv[3]*dv[3];

    bf16x4 qo, ko;
    #pragma unroll
    for (int i = 0; i < 4; ++i) { qo[i] = (bf16_t)qv[i]; ko[i] = (bf16_t)kv[i]; }

    const int G = p >> 5, l31 = p & 31;
    const int kk = lane >> 2, h = (lane >> 1) & 1, j0 = (lane & 1) * 4;
    const size_t base = (size_t)G * GS;
    const size_t off  = base + (size_t)(kk * 64 + h * 32 + l31) * 8 + j0;
    *(bf16x4*)(qb2 + off) = qo;
    *(bf16x4*)(kb2 + off) = ko;

    #pragma unroll
    for (int s = 32; s > 0; s >>= 1) {
        qs += __shfl_xor(qs, s);
        ks += __shfl_xor(ks, s);
        ds += __shfl_xor(ds, s);
    }

    // Pad frag kk=16 (dims 256..271). q' = [qhi,qlo,1,1,0..], k' = [1,1,khi,klo,0..]
    // so extra-dim dot = -(qs+ks)/2 with bf16 hi/lo split (norm error < 0.01).
    if (lane < 4) {
        const int hh = lane & 1;           // h of the pad block this lane writes
        bf16x8 v;
        #pragma unroll
        for (int i = 0; i < 8; ++i) v[i] = (bf16_t)0.0f;
        if (lane == 0) {                   // q', dims 256..263
            const float qh = -0.5f * qs;
            const bf16_t q1 = (bf16_t)qh;
            v[0] = q1; v[1] = (bf16_t)(qh - (float)q1);
            v[2] = (bf16_t)1.0f; v[3] = (bf16_t)1.0f;
        } else if (lane == 2) {            // k', dims 256..263
            const float kh = -0.5f * ks;
            const bf16_t k1 = (bf16_t)kh;
            v[0] = (bf16_t)1.0f; v[1] = (bf16_t)1.0f;
            v[2] = k1; v[3] = (bf16_t)(kh - (float)k1);
        }
        bf16_t* dstp = (lane < 2) ? qb2 : kb2;
        *(bf16x8*)(dstp + base + (size_t)(1024 + hh * 32 + l31) * 8) = v;
    }
    if (lane == 0)
        diag2[p] = (float)(-C2) * __builtin_amdgcn_sqrtf(ds);  // exact diag, log2
}

// ---------------------------------------------------------------------------
// ROUND-13: REGISTER-RESIDENT L2 STREAMING — no LDS, no barriers.
// Closed model from R6-R12: (a) MFMA BLOCKS ITS WAVE (no async MFMA), so
// 1 wave/SIMD can never overlap anything -> the 25% band of R6-R11;
// (b) 2 waves/SIMD needs <=256 regs, which with LDS staging forced RG=1 ->
// 1:1 ds_read:MFMA -> LDS-pipe floor 3264 cyc/phase = R12's 50us (87% LDS
// util measured).  Escape: B is L2-resident (557 KB/XCD working set) —
// stream B-frags straight from global into registers:
//   - RG=2: each B-frag load feeds 2 MFMAs -> total B traffic 557 MB ->
//     L2 floor ~16us; MFMA floor 14.5us — balanced.
//   - regs: A 136 + acc 32 + l 32 + B-quad window 16 + temps ~25 = ~240
//     <= 256 -> 2 waves/SIMD (staging/barrier temps that pushed R6 to ~280
//     are gone).
//   - NO sync anywhere in the main loop: waves fully independent; wave A's
//     L2 latency hides under wave B's blocking MFMAs.
// Partition: 2048 waves = 512 blocks x 4; wave = 2 row-groups x all 16
// col-groups of its stripe.  XCD mapping: each XCD owns 2 col-stripes
// (2 x 512 cols x 272 x 2B = 557 KB B working set, L2-resident); A re-reads
// (70 MB total) absorbed by L3.
// ---------------------------------------------------------------------------
__global__ __launch_bounds__(256, 2) void nce_main(
    const bf16_t* __restrict__ qb2, const bf16_t* __restrict__ kb2,
    const float* __restrict__ diag2, float* __restrict__ part_l,
    unsigned* __restrict__ cnt, float* __restrict__ out)
{
    const int tid  = threadIdx.x, wave = tid >> 6, lane = tid & 63;
    const int l31  = lane & 31, h = lane >> 5;

    // bid -> xcd (HW: bid%8) -> stripe pair; idx within XCD -> row-position
    const int bid = blockIdx.x;
    const int xcd = bid & 7, idx = bid >> 3;          // idx 0..63
    const int by  = xcd * 2 + (idx >> 5);             // col-stripe 0..15
    const int bxi = idx & 31;                         // row-block 0..31
    const int G0  = bxi * 8 + wave * 2;               // wave's first 32-row group

    __shared__ int s_last;
    __shared__ float red[4];

    // A fragments for 2 row groups: 2 x 17 x 4 = 136 regs, 1KB/instr coalesced
    bf16x8 a0[NKF], a1[NKF];
    {
        const bf16_t* ap0 = qb2 + (size_t)G0 * GS + lane * 8;
        const bf16_t* ap1 = ap0 + GS;
        #pragma unroll
        for (int kk = 0; kk < NKF; ++kk) {
            a0[kk] = *(const bf16x8*)(ap0 + kk * 512);
            a1[kk] = *(const bf16x8*)(ap1 + kk * 512);
        }
    }

    float l0[16], l1[16];
    #pragma unroll
    for (int i = 0; i < 16; ++i) { l0[i] = 0.0f; l1[i] = 0.0f; }

    // main loop: 16 col-group tiles, B streamed from L2 into registers.
    // Quad-structured so only ~8 B-frags are live at once (reg budget).
    #pragma unroll 1
    for (int t = 0; t < TPC; ++t) {
        const int cg = by * TPC + t;
        const bf16_t* bp = kb2 + (size_t)cg * GS + lane * 8;
        f32x16 acc0 = {0,0,0,0,0,0,0,0,0,0,0,0,0,0,0,0};
        f32x16 acc1 = {0,0,0,0,0,0,0,0,0,0,0,0,0,0,0,0};
        #pragma unroll
        for (int kq = 0; kq < 4; ++kq) {
            const bf16x8 b0 = *(const bf16x8*)(bp + (kq * 4 + 0) * 512);
            const bf16x8 b1 = *(const bf16x8*)(bp + (kq * 4 + 1) * 512);
            const bf16x8 b2 = *(const bf16x8*)(bp + (kq * 4 + 2) * 512);
            const bf16x8 b3 = *(const bf16x8*)(bp + (kq * 4 + 3) * 512);
            acc0 = __builtin_amdgcn_mfma_f32_32x32x16_bf16(a0[kq*4+0], b0, acc0,0,0,0);
            acc1 = __builtin_amdgcn_mfma_f32_32x32x16_bf16(a1[kq*4+0], b0, acc1,0,0,0);
            acc0 = __builtin_amdgcn_mfma_f32_32x32x16_bf16(a0[kq*4+1], b1, acc0,0,0,0);
            acc1 = __builtin_amdgcn_mfma_f32_32x32x16_bf16(a1[kq*4+1], b1, acc1,0,0,0);
            acc0 = __builtin_amdgcn_mfma_f32_32x32x16_bf16(a0[kq*4+2], b2, acc0,0,0,0);
            acc1 = __builtin_amdgcn_mfma_f32_32x32x16_bf16(a1[kq*4+2], b2, acc1,0,0,0);
            acc0 = __builtin_amdgcn_mfma_f32_32x32x16_bf16(a0[kq*4+3], b3, acc0,0,0,0);
            acc1 = __builtin_amdgcn_mfma_f32_32x32x16_bf16(a1[kq*4+3], b3, acc1,0,0,0);
        }
        {
            const bf16x8 bl = *(const bf16x8*)(bp + 16 * 512);
            acc0 = __builtin_amdgcn_mfma_f32_32x32x16_bf16(a0[16], bl, acc0,0,0,0);
            acc1 = __builtin_amdgcn_mfma_f32_32x32x16_bf16(a1[16], bl, acc1,0,0,0);
        }
        // acc = -dist^2/2.  2^(lg-MEXP) bitcast trick; negative -> clamp 0
        #pragma unroll
        for (int i = 0; i < 16; ++i) {
            const float t0 = __builtin_amdgcn_sqrtf(-acc0[i]);
            const float u0 = fmaxf(fmaf(t0, COEF, KBIAS), 0.0f);
            l0[i] += __uint_as_float((unsigned)u0);
            const float t1 = __builtin_amdgcn_sqrtf(-acc1[i]);
            const float u1 = fmaxf(fmaf(t1, COEF, KBIAS), 0.0f);
            l1[i] += __uint_as_float((unsigned)u1);
        }
    }

    // sum l across the 32 column-lanes (plain adds — fixed shift, no max merge)
    #pragma unroll
    for (int s = 1; s < 32; s <<= 1) {
        #pragma unroll
        for (int i = 0; i < 16; ++i) {
            l0[i] += __shfl_xor(l0[i], s);
            l1[i] += __shfl_xor(l1[i], s);
        }
    }

    if (l31 == 0) {
        #pragma unroll
        for (int i = 0; i < 16; ++i) {
            const int r = (i & 3) + 8 * (i >> 2) + 4 * h;
            atomicAdd(&part_l[G0 * 32 + r], l0[i]);
            atomicAdd(&part_l[(G0 + 1) * 32 + r], l1[i]);
        }
    }

    __syncthreads();
    if (tid == 0) {
        __threadfence();
        s_last = (atomicAdd(&cnt[bxi], 1u) == NSTRIPE - 1) ? 1 : 0;
    }
    __syncthreads();
    if (s_last) {
        // all 16 stripe-blocks of this row-block done: finalize 256 rows
        const int row = bxi * ROWBLK + tid;
        const float lf = atomicAdd(&part_l[row], 0.0f);   // coherent read
        float v = MEXP + __builtin_amdgcn_logf(lf) - diag2[row];  // log2 domain
        #pragma unroll
        for (int s = 1; s < 64; s <<= 1) v += __shfl_xor(v, s);
        if (lane == 0) red[wave] = v;
        __syncthreads();
        if (tid == 0)
            atomicAdd(out, (red[0] + red[1] + red[2] + red[3]) * (LN2 / (float)PP));
    }
}

// ---------------------------------------------------------------------------
extern "C" void kernel_launch(void* const* d_in, const int* in_sizes, int n_in,
                              void* d_out, int out_size, void* d_ws, size_t ws_size,
                              hipStream_t stream)
{
    const float* f1  = (const float*)d_in[0];   // [20000,256] f32
    const float* f2  = (const float*)d_in[1];   // [8192,256] f32
    const int*   map = (const int*)d_in[2];     // [8192] int
    float* out = (float*)d_out;

    // workspace layout (~8.98 MB)
    char* ws = (char*)d_ws;
    bf16_t*   qb2    = (bf16_t*)ws;                           // 256*8704*2 B
    bf16_t*   kb2    = qb2 + (size_t)256 * GS;                // 256*8704*2 B
    float*    diag2  = (float*)(ws + 2ull * 256 * GS * sizeof(bf16_t));
    float*    part_l = diag2 + PP;
    unsigned* cnt    = (unsigned*)(part_l + PP);

    nce_prep<<<PP / 4, 256, 0, stream>>>(f1, f2, map, qb2, kb2, diag2,
                                         part_l, cnt, out);
    nce_main<<<512, 256, 0, stream>>>(qb2, kb2, diag2, part_l, cnt, out);
}